// Round 11
// baseline (2634.491 us; speedup 1.0000x reference)
//
#include <hip/hip_runtime.h>

#define TT 2048
#define II 64
#define HH 256
#define MPB 16    // batches per block -> 4 blocks
#define RING 32   // head-partial ring depth (steps)

typedef __fp16 f16x8 __attribute__((ext_vector_type(8)));
typedef float  f32x4 __attribute__((ext_vector_type(4)));

#define MFMA(a, b, c) __builtin_amdgcn_mfma_f32_16x16x32_f16((a), (b), (c), 0, 0, 0)

// pack 8 fp32 -> f16x8 fragment
__device__ __forceinline__ f16x8 pack8(float4 a, float4 b) {
    int4 iv;
    iv.x = __builtin_bit_cast(int, __builtin_amdgcn_cvt_pkrtz(a.x, a.y));
    iv.y = __builtin_bit_cast(int, __builtin_amdgcn_cvt_pkrtz(a.z, a.w));
    iv.z = __builtin_bit_cast(int, __builtin_amdgcn_cvt_pkrtz(b.x, b.y));
    iv.w = __builtin_bit_cast(int, __builtin_amdgcn_cvt_pkrtz(b.z, b.w));
    return __builtin_bit_cast(f16x8, iv);
}

// tanh(x) = 1 - 2/(e^{2x}+1)
__device__ __forceinline__ float ftanh(float x) {
    float e = __expf(2.0f * x);
    return 1.0f - 2.0f * __builtin_amdgcn_rcpf(e + 1.0f);
}

// 4 blocks x 512 thr = 8 waves, 2/SIMD (R10 ran 1/SIMD -> naked latency).
// Per step: D = W x h (A = weights, B = h/x frags; C col = batch, row =
// hidden — the R10-verified arrangement). Wave w owns hidden cols
// [w*32, w*32+32) = 2 tiles x 10 k-blocks; B-tile = 80 pinned VGPRs.
// hbuf frag-ready layout: (batch m, k) at half (k>>5)*512+((k>>3)&3)*128
// +m*8+(k&7); lane reads frag kb at lane*8+kb*512 (dense, conflict-free).
// Head (NO wave-0 straggler, NO atomics): each thread folds its 8 post-tanh
// h-values with W_fc (8 fma) and ds_writes ONE f32 partial into a 32-step
// ring; a drain phase every 32 steps sums 32 partials/(t,batch) and writes
// out coalesced. Partial order in the ring is permuted (bank stagger) —
// sum is order-invariant.
__launch_bounds__(512, 2)
__global__ void rnn_mfma(const float* __restrict__ x,
                         const float* __restrict__ W_ih,
                         const float* __restrict__ W_hh,
                         const float* __restrict__ b_ih,
                         const float* __restrict__ b_hh,
                         const float* __restrict__ W_fc,
                         const float* __restrict__ b_fc,
                         float* __restrict__ out) {
    __shared__ __align__(16) __fp16 hbuf[2][4096];   // 16 KB double-buffered h
    __shared__ __align__(16) float ring[RING * 512]; // 64 KB head partials

    const int tid  = threadIdx.x;
    const int b0   = blockIdx.x;
    const int lane = tid & 63;
    const int w    = tid >> 6;   // wave 0..7 -> hidden cols [w*32, w*32+32)
    const int nl   = lane & 15;  // A: hidden-in-tile / B,C: batch
    const int g    = lane >> 4;  // k-subgroup / C row-group
    const int g2   = g * 2;

    // ---- A-fragments (weights) pinned; bias + head weights per C row ----
    f16x8 wb[2][10];
    f32x4 biasv[2], wfcv[2];
#pragma unroll
    for (int tt = 0; tt < 2; ++tt) {
        const int col = w * 32 + tt * 16 + nl;
        const float* wrow = W_hh + col * HH + g * 8;
#pragma unroll
        for (int kb = 0; kb < 8; ++kb) {
            const float4* p = (const float4*)(wrow + kb * 32);
            wb[tt][kb] = pack8(p[0], p[1]);
        }
        const float* irow = W_ih + col * II + g * 8;
        { const float4* p = (const float4*)irow;        wb[tt][8] = pack8(p[0], p[1]); }
        { const float4* p = (const float4*)(irow + 32); wb[tt][9] = pack8(p[0], p[1]); }
#pragma unroll
        for (int r = 0; r < 4; ++r) {
            const int hc = w * 32 + tt * 16 + g * 4 + r;  // C row -> hidden unit
            biasv[tt][r] = b_ih[hc] + b_hh[hc];
            wfcv[tt][r]  = W_fc[hc];
        }
    }
#pragma unroll
    for (int tt = 0; tt < 2; ++tt)
#pragma unroll
        for (int kb = 0; kb < 10; ++kb) asm volatile("" : "+v"(wb[tt][kb]));

    const float bfc = b_fc[0];

    for (int idx = tid; idx < 2 * 4096; idx += 512) ((__fp16*)hbuf)[idx] = (__fp16)0.0f;
    __syncthreads();

    const __fp16* hrd = (const __fp16*)hbuf + lane * 8;  // B-frag read base
    __fp16* hba = (__fp16*)hbuf;
    // packed b64 h-write base per tile (halfs); r packed in-register
    int wb64[2];
#pragma unroll
    for (int tt = 0; tt < 2; ++tt)
        wb64[tt] = w * 512 + (tt * 2 + (g >> 1)) * 128 + nl * 8 + (g & 1) * 4;

    // ring slot-internal index: batch-major, bank-staggered permutation
    const int rbase = nl * 32 + ((g * 8 + w + nl * 4) & 31);

    const float* xrow = x + (size_t)(b0 * MPB + nl) * TT * II;
    float4 xa0, xa1, xb0, xb1;
    {
        const float4* xp = (const float4*)xrow + g2;        xa0 = xp[0]; xa1 = xp[1];
        const float4* xq = (const float4*)(xrow + 32) + g2; xb0 = xq[0]; xb1 = xq[1];
    }

#define STEP(i, P) do {                                                          \
    f16x8 af[10];                                                                \
    af[8] = pack8(xa0, xa1);                                                     \
    af[9] = pack8(xb0, xb1);                                                     \
    { const float* xn = xrow + (size_t)(((i) + 1 < TT) ? (i) + 1 : (i)) * II;    \
      const float4* xp = (const float4*)xn + g2;        xa0 = xp[0]; xa1 = xp[1];\
      const float4* xq = (const float4*)(xn + 32) + g2; xb0 = xq[0]; xb1 = xq[1];}\
    _Pragma("unroll")                                                            \
    for (int kb = 0; kb < 8; ++kb)                                               \
        af[kb] = *(const f16x8*)(hrd + (P) * 4096 + kb * 512);                   \
    f32x4 c[2], cb[2];                                                           \
    _Pragma("unroll")                                                            \
    for (int tt = 0; tt < 2; ++tt) { c[tt] = biasv[tt]; cb[tt] = (f32x4){0,0,0,0}; } \
    _Pragma("unroll")                                                            \
    for (int kk = 0; kk < 5; ++kk) {                                             \
        _Pragma("unroll")                                                        \
        for (int tt = 0; tt < 2; ++tt) c[tt]  = MFMA(wb[tt][2*kk],   af[2*kk],   c[tt]);  \
        _Pragma("unroll")                                                        \
        for (int tt = 0; tt < 2; ++tt) cb[tt] = MFMA(wb[tt][2*kk+1], af[2*kk+1], cb[tt]); \
    }                                                                            \
    float hp = 0.0f;                                                             \
    _Pragma("unroll")                                                            \
    for (int tt = 0; tt < 2; ++tt) {                                             \
        const float h0 = ftanh(c[tt][0] + cb[tt][0]);                            \
        const float h1 = ftanh(c[tt][1] + cb[tt][1]);                            \
        const float h2 = ftanh(c[tt][2] + cb[tt][2]);                            \
        const float h3 = ftanh(c[tt][3] + cb[tt][3]);                            \
        int2 pk;                                                                 \
        pk.x = __builtin_bit_cast(int, __builtin_amdgcn_cvt_pkrtz(h0, h1));      \
        pk.y = __builtin_bit_cast(int, __builtin_amdgcn_cvt_pkrtz(h2, h3));      \
        *(int2*)(hba + ((P) ^ 1) * 4096 + wb64[tt]) = pk;                        \
        hp = fmaf(h0, wfcv[tt][0], hp);                                          \
        hp = fmaf(h1, wfcv[tt][1], hp);                                          \
        hp = fmaf(h2, wfcv[tt][2], hp);                                          \
        hp = fmaf(h3, wfcv[tt][3], hp);                                          \
    }                                                                            \
    ring[(((i) & (RING - 1)) << 9) + rbase] = hp;                                \
    __syncthreads();                                                             \
} while (0)

    for (int i0 = 0; i0 < TT; i0 += RING) {
#pragma unroll 2
        for (int ii = 0; ii < RING; ii += 2) {
            STEP(i0 + ii, 0);
            STEP(i0 + ii + 1, 1);
        }
        // ---- drain: out[b][i0+s] = sum of 32 partials + bfc ----
        {
            const int m = tid >> 5, s = tid & 31;
            const float4* rp = (const float4*)&ring[(s << 9) + m * 32];
            float acc = bfc;
#pragma unroll
            for (int j = 0; j < 8; ++j) {
                const int jj = (j + (tid & 7)) & 7;  // bank stagger
                const float4 v = rp[jj];
                acc += v.x + v.y + v.z + v.w;
            }
            out[(size_t)(b0 * MPB + m) * TT + i0 + s] = acc;
        }
        __syncthreads();  // guard ring-slot reuse by the next window
    }
#undef STEP
}

extern "C" void kernel_launch(void* const* d_in, const int* in_sizes, int n_in,
                              void* d_out, int out_size, void* d_ws, size_t ws_size,
                              hipStream_t stream) {
    const float* x    = (const float*)d_in[0];
    const float* W_ih = (const float*)d_in[1];
    const float* W_hh = (const float*)d_in[2];
    const float* b_ih = (const float*)d_in[3];
    const float* b_hh = (const float*)d_in[4];
    const float* W_fc = (const float*)d_in[5];
    const float* b_fc = (const float*)d_in[6];
    float* out = (float*)d_out;

    rnn_mfma<<<64 / MPB, 512, 0, stream>>>(x, W_ih, W_hh, b_ih, b_hh, W_fc, b_fc, out);
}